// Round 14
// baseline (45.261 us; speedup 1.0000x reference)
//
#include <hip/hip_runtime.h>
#include <cstdint>

typedef unsigned long long u64;
typedef unsigned int u32;
typedef int v4i __attribute__((ext_vector_type(4)));

#define BB 64
#define DD 128
#define OO 512
#define II 512             // elements (bytes in mode 0) per row
#define OT 64              // o-tile per block -> 1024 blocks

// ---------------------------------------------------------------------------
// Input-format detection. mode 0: bytes {0,1} | 1: int32 {0,1} | 2: f32 {0,1}
// Mode 0 is confirmed executed (cold FETCH 74MB << int32's 134MB compulsory).
// ---------------------------------------------------------------------------
__device__ __forceinline__ int detect_mode(const u32* __restrict__ w) {
    bool all01 = true, allf = true;
#pragma unroll
    for (int i = 0; i < 32; ++i) {
        u32 v = w[i];
        all01 = all01 && (v <= 1u);
        allf  = allf  && (v == 0u || v == 0x3F800000u);
    }
    return all01 ? 1 : (allf ? 2 : 0);
}

// Async global->LDS DMA, 16B/lane (1KB per wave-instr). LDS dest must be the
// wave-uniform base (HW adds lane*16); global src is per-lane (gather OK).
__device__ __forceinline__ void gload_lds16(const void* g, void* lds) {
    __builtin_amdgcn_global_load_lds(
        (const __attribute__((address_space(1))) void*)g,
        (__attribute__((address_space(3))) void*)lds, 16, 0, 0);
}

// Ballot row packer (fallback modes 1/2 only; lane j<8 keeps word j).
__device__ __forceinline__ u64 pack_row_ballot(const void* __restrict__ src,
                                               size_t elem0, int mode, int lane) {
    const u32 sh = (mode == 1) ? 0u : 23u;
    const uint4* p = (const uint4*)((const u32*)src + elem0);
    uint4 a = p[lane];
    uint4 b = p[64 + lane];
    u64 w0 = __ballot((a.x >> sh) & 1u), w1 = __ballot((a.y >> sh) & 1u);
    u64 w2 = __ballot((a.z >> sh) & 1u), w3 = __ballot((a.w >> sh) & 1u);
    u64 w4 = __ballot((b.x >> sh) & 1u), w5 = __ballot((b.y >> sh) & 1u);
    u64 w6 = __ballot((b.z >> sh) & 1u), w7 = __ballot((b.w >> sh) & 1u);
    u64 my = 0;
    if (lane == 0) my = w0;  if (lane == 1) my = w1;
    if (lane == 2) my = w2;  if (lane == 3) my = w3;
    if (lane == 4) my = w4;  if (lane == 5) my = w5;
    if (lane == 6) my = w6;  if (lane == 7) my = w7;
    return my;
}

// ---------------------------------------------------------------------------
// MFMA-i8 kernel. Block = (d, 64-wide o-tile); 1024 blocks; LDS ~64.5KB ->
// 2 blocks/CU. matches = I - sum_w - sum_x + 2*dot computed as:
//   dot  : mfma_i32_16x16x32_i8 over raw {0,1} bytes (NO bit packing)
//   sums : byte-sum multiply trick from the staged LDS tiles
// Staging: global_load_lds with a 16B-chunk XOR swizzle (chunk c of row r
// stored at LDS chunk c, sourced from global chunk c^(r&7)) so stride-512
// fragment reads are <=2-way bank conflicts. Sums are order-invariant.
// A k-slot convention identical for A and B makes the dot exact regardless
// of the HW slot->k map (k-permutation invariance); C/D map is m89-verified:
// col = lane&15, row = (lane>>4)*4 + reg.
// ---------------------------------------------------------------------------
__global__ __launch_bounds__(256, 2)
void binlin_mfma(const void* __restrict__ x, const void* __restrict__ w,
                 const float* __restrict__ bias, int* __restrict__ out) {
    __shared__ __align__(16) uint8_t xa[BB * II];     // 32 KB x tile (raw)
    __shared__ __align__(16) uint8_t wt[OT * II];     // 32 KB w tile (raw)
    __shared__ int sumx[BB];
    __shared__ int sumw[OT];

    const int tid  = threadIdx.x;
    const int bid  = blockIdx.x;
    const int xcd  = bid & 7;
    const int idx  = bid >> 3;           // 0..127
    const int d    = xcd * 16 + (idx >> 3);
    const int o0   = (idx & 7) * OT;
    const int wv   = tid >> 6;
    const int lane = tid & 63;

    const int mode = detect_mode((const u32*)w);

    if (mode == 0) {
        const uint8_t* wg = (const uint8_t*)w + (size_t)(d * OO + o0) * II;
        const uint8_t* xg = (const uint8_t*)x;

        // ---- stage 64KB via DMA: 32 instrs (8/wave each tensor) ----
#pragma unroll
        for (int j = 0; j < 8; ++j) {
            const int i  = wv * 8 + j;               // 1KB chunk: rows 2i,2i+1
            const int rr = 2 * i + (lane >> 5);
            const int cc = lane & 31;
            gload_lds16(wg + (size_t)rr * II + ((cc ^ (rr & 7)) << 4),
                        wt + i * 1024);
        }
#pragma unroll
        for (int j = 0; j < 8; ++j) {
            const int i  = wv * 8 + j;
            const int rr = 2 * i + (lane >> 5);
            const int cc = lane & 31;
            gload_lds16(xg + ((size_t)rr * DD + d) * II + ((cc ^ (rr & 7)) << 4),
                        xa + i * 1024);
        }
        asm volatile("s_waitcnt vmcnt(0)" ::: "memory");
        __syncthreads();

        // ---- row sums: 128 rows, one thread each (order-invariant) ----
        if (tid < 128) {
            const uint8_t* row = (tid < 64) ? (xa + (size_t)tid * II)
                                            : (wt + (size_t)(tid - 64) * II);
            int s = 0;
#pragma unroll
            for (int q = 0; q < 32; ++q) {
                uint4 v = *(const uint4*)(row + q * 16);
                s += (int)((v.x * 0x01010101u) >> 24)
                   + (int)((v.y * 0x01010101u) >> 24)
                   + (int)((v.z * 0x01010101u) >> 24)
                   + (int)((v.w * 0x01010101u) >> 24);
                q += 1;  // uint4 covers 16B; 32 iters would double-count
                (void)0;
            }
            // NOTE: loop above strides 2 via the inner q+=1 (reads q=0,2,..30
            // -> 16 uint4 = 256B). Second half below.
            const uint8_t* row2 = row + 256;
#pragma unroll
            for (int q = 0; q < 16; ++q) {
                uint4 v = *(const uint4*)(row2 + q * 16);
                s += (int)((v.x * 0x01010101u) >> 24)
                   + (int)((v.y * 0x01010101u) >> 24)
                   + (int)((v.z * 0x01010101u) >> 24)
                   + (int)((v.w * 0x01010101u) >> 24);
            }
            if (tid < 64) sumx[tid] = s; else sumw[tid - 64] = s;
        }
        __syncthreads();

        // ---- MFMA K-loop: 4 n-tiles x 16 K-steps = 64 MFMA/wave ----
        const int mr   = wv * 16 + (lane & 15);      // A row (b)
        const int nr   = lane & 15;                  // B row within n-tile
        const int kg   = lane >> 4;                  // k-group 0..3
        const int axor = mr & 7;
        const int bxor = nr & 7;                     // (16+nr)&7 == nr&7 etc.
        const uint8_t* arow  = xa + (size_t)mr * II;
        const uint8_t* brow0 = wt + (size_t)nr * II;
        const uint8_t* brow1 = wt + (size_t)(16 + nr) * II;
        const uint8_t* brow2 = wt + (size_t)(32 + nr) * II;
        const uint8_t* brow3 = wt + (size_t)(48 + nr) * II;

        v4i acc0 = {0, 0, 0, 0}, acc1 = {0, 0, 0, 0};
        v4i acc2 = {0, 0, 0, 0}, acc3 = {0, 0, 0, 0};
#pragma unroll
        for (int kk = 0; kk < 16; ++kk) {
            const int kb = kk * 32 + kg * 8;         // byte offset in row
            const int ch = kb >> 4;                  // 16B chunk index
            const int ic = kb & 15;                  // 0 or 8
            long a  = *(const long*)(arow  + ((ch ^ axor) << 4) + ic);
            long b0 = *(const long*)(brow0 + ((ch ^ bxor) << 4) + ic);
            long b1 = *(const long*)(brow1 + ((ch ^ bxor) << 4) + ic);
            long b2 = *(const long*)(brow2 + ((ch ^ bxor) << 4) + ic);
            long b3 = *(const long*)(brow3 + ((ch ^ bxor) << 4) + ic);
            acc0 = __builtin_amdgcn_mfma_i32_16x16x32_i8(a, b0, acc0, 0, 0, 0);
            acc1 = __builtin_amdgcn_mfma_i32_16x16x32_i8(a, b1, acc1, 0, 0, 0);
            acc2 = __builtin_amdgcn_mfma_i32_16x16x32_i8(a, b2, acc2, 0, 0, 0);
            acc3 = __builtin_amdgcn_mfma_i32_16x16x32_i8(a, b3, acc3, 0, 0, 0);
        }

        // ---- epilogue: act = 512 - sum_w - sum_x + 2*dot; cmp bias ----
        const int mloc = wv * 16 + (lane >> 4) * 4;  // base b of my 4 regs
#define EPI(T, ACC)                                                          \
        {                                                                    \
            const int o  = o0 + (T) * 16 + nr;                               \
            const float bv = bias[d * OO + o];                               \
            const int sw = sumw[(T) * 16 + nr];                              \
            _Pragma("unroll")                                                \
            for (int j = 0; j < 4; ++j) {                                    \
                const int b   = mloc + j;                                    \
                const int act = II - sw - sumx[b] + 2 * (ACC)[j];            \
                out[(size_t)b * (DD * OO) + d * OO + o] =                    \
                    ((float)act > bv) ? 1 : 0;                               \
            }                                                                \
        }
        EPI(0, acc0) EPI(1, acc1) EPI(2, acc2) EPI(3, acc3)
#undef EPI
    } else {
        // ---- fallback (int32/f32): ballot pack + popcount (R7 path) ----
        u64 (*wp)[9] = (u64 (*)[9])wt;               // 4.6 KB carve
        u64 (*xp)[9] = (u64 (*)[9])xa;
        const float bv = bias[d * OO + o0 + (tid & 63)];
#pragma unroll
        for (int r = 0; r < 16; ++r) {
            const int o = wv * 16 + r;
            u64 my = pack_row_ballot(w, ((size_t)(d * OO + o0 + o)) * II, mode, lane);
            if (lane < 8) wp[o][lane] = my;
        }
#pragma unroll
        for (int r = 0; r < 16; ++r) {
            const int b = wv * 16 + r;
            u64 my = pack_row_ballot(x, ((size_t)(b * DD + d)) * II, mode, lane);
            if (lane < 8) xp[b][lane] = my;
        }
        __syncthreads();
        const int o  = tid & 63;
        const int b0 = (tid >> 6) * 16;
        u64 wr[8];
#pragma unroll
        for (int k = 0; k < 8; ++k) wr[k] = wp[o][k];
        int* outp = out + (size_t)d * OO + o0 + o;
#pragma unroll 4
        for (int bi = 0; bi < 16; ++bi) {
            const int b = b0 + bi;
            int m = 0;
#pragma unroll
            for (int k = 0; k < 8; ++k) m += __popcll(xp[b][k] ^ wr[k]);
            const float act = (float)(512 - m);
            outp[(size_t)b * (DD * OO)] = (act > bv) ? 1 : 0;
        }
    }
}

extern "C" void kernel_launch(void* const* d_in, const int* in_sizes, int n_in,
                              void* d_out, int out_size, void* d_ws, size_t ws_size,
                              hipStream_t stream) {
    const void*  x    = d_in[0];                 // (B, D, I) binary bytes
    const void*  w    = d_in[1];                 // (D, O, I) binary bytes
    const float* bias = (const float*)d_in[2];   // (D, O) f32
    int*         out  = (int*)d_out;             // (B, D, O) bool as int32

    binlin_mfma<<<DD * (OO / OT), 256, 0, stream>>>(x, w, bias, out);
}

// Round 15
// 36.870 us; speedup vs baseline: 1.2276x; 1.2276x over previous
//
#include <hip/hip_runtime.h>
#include <cstdint>

typedef unsigned long long u64;
typedef unsigned int u32;

#define BB 64
#define DD 128
#define OO 512
#define II 512             // elements (bytes in mode 0) per row
#define SOT 32             // o-subtile (pipeline stage, 16KB raw)
#define NSUB 4             // subtiles per block
#define BOT (SOT * NSUB)   // 128 o per block -> 512 blocks

// ---------------------------------------------------------------------------
// Input-format detection. mode 0: bytes {0,1} | 1: int32 {0,1} | 2: f32 {0,1}
// Mode 0 confirmed executed (cold FETCH 74MB << int32's 134MB compulsory).
// ---------------------------------------------------------------------------
__device__ __forceinline__ int detect_mode(const u32* __restrict__ w) {
    bool all01 = true, allf = true;
#pragma unroll
    for (int i = 0; i < 32; ++i) {
        u32 v = w[i];
        all01 = all01 && (v <= 1u);
        allf  = allf  && (v == 0u || v == 0x3F800000u);
    }
    return all01 ? 1 : (allf ? 2 : 0);
}

// 8 ballots pack one row's 512 bytes (lane holds bytes [8L,8L+8) as LE u64)
// into 8 u64 words; lane j (j<8) keeps word j. Bijection (elem 8L+j -> word
// j bit L) used identically for x and w -> popcount(xor) counts mismatches.
__device__ __forceinline__ u64 ballots8_bytes(u64 v, int lane) {
    u64 keep = 0;
#pragma unroll
    for (int j = 0; j < 8; ++j) {
        u64 bj = __ballot((u32)(v >> (8 * j)) & 1u);
        if (lane == j) keep = bj;
    }
    return keep;
}

// Ballot row packer from global (modes 1/2 fallback; lane j<8 keeps word j).
__device__ __forceinline__ u64 pack_row_ballot(const void* __restrict__ src,
                                               size_t elem0, int mode, int lane) {
    const u32 sh = (mode == 1) ? 0u : 23u;
    const uint4* p = (const uint4*)((const u32*)src + elem0);
    uint4 a = p[lane];
    uint4 b = p[64 + lane];
    u64 w0 = __ballot((a.x >> sh) & 1u), w1 = __ballot((a.y >> sh) & 1u);
    u64 w2 = __ballot((a.z >> sh) & 1u), w3 = __ballot((a.w >> sh) & 1u);
    u64 w4 = __ballot((b.x >> sh) & 1u), w5 = __ballot((b.y >> sh) & 1u);
    u64 w6 = __ballot((b.z >> sh) & 1u), w7 = __ballot((b.w >> sh) & 1u);
    u64 my = 0;
    if (lane == 0) my = w0;  if (lane == 1) my = w1;
    if (lane == 2) my = w2;  if (lane == 3) my = w3;
    if (lane == 4) my = w4;  if (lane == 5) my = w5;
    if (lane == 6) my = w6;  if (lane == 7) my = w7;
    return my;
}

// Async global->LDS DMA, 16B/lane (1KB per wave-instr). Global src per-lane;
// LDS dest = wave-uniform base + lane*16 (linear).
__device__ __forceinline__ void gload_lds16(const void* g, void* lds) {
    __builtin_amdgcn_global_load_lds(
        (const __attribute__((address_space(1))) void*)g,
        (__attribute__((address_space(3))) void*)lds, 16, 0, 0);
}

// ---------------------------------------------------------------------------
// Streaming kernel. 512 blocks (2/CU), block = (d, 128-o range), 4 subtile
// iterations. Double-buffered DMA: subtile t+1's 16KB w-stream is issued at
// the top of iter t and lands while t is packed+computed -> the HBM stream
// never stops (the one-generation burst stall of rounds 2-14 was the wall).
// All LDS pack reads are lane-adjacent (conflict-free, linear layout).
// Phase C: thread owns o = tid&31 of subtile and 8 b's:
//   matches = 512 - popcount(x ^ w); out = (matches > bias) as int32.
// ---------------------------------------------------------------------------
__global__ __launch_bounds__(256, 2)
void binlin_stream(const void* __restrict__ x, const void* __restrict__ w,
                   const float* __restrict__ bias, int* __restrict__ out) {
    __shared__ __align__(16) uint8_t xraw[BB * II];       // 32KB raw x slice
    __shared__ __align__(16) uint8_t wraw[2][SOT * II];   // 2x16KB w dbuf
    __shared__ u64 xp[BB][9];                             // packed x (+pad)
    __shared__ u64 wp[SOT][9];                            // packed w subtile

    const int tid  = threadIdx.x;
    const int bid  = blockIdx.x;
    const int xcd  = bid & 7;
    const int idx  = bid >> 3;           // 0..63
    const int d    = xcd * 16 + (idx >> 2);
    const int ob   = (idx & 3) * BOT;    // o-range base
    const int wv   = tid >> 6;
    const int lane = tid & 63;

    const int mode = detect_mode((const u32*)w);

    // bias preload (one per subtile) so Phase C issues no global loads
    float bvv[NSUB];
#pragma unroll
    for (int t = 0; t < NSUB; ++t)
        bvv[t] = bias[d * OO + ob + t * SOT + (tid & 31)];

    if (mode == 0) {
        const uint8_t* wg = (const uint8_t*)w + ((size_t)d * OO + ob) * II;
        const uint8_t* xg = (const uint8_t*)x;

        // ---- prologue DMA: w subtile 0 (16x1KB) + x slice (32x1KB) ----
#pragma unroll
        for (int j = 0; j < 4; ++j) {
            const int i = wv * 4 + j;
            gload_lds16(wg + (size_t)i * 1024 + (size_t)lane * 16,
                        wraw[0] + i * 1024);
        }
#pragma unroll
        for (int j = 0; j < 8; ++j) {
            const int i = wv * 8 + j;                // chunk = x rows 2i,2i+1
            const int b = 2 * i + (lane >> 5);
            gload_lds16(xg + ((size_t)b * DD + d) * II + (size_t)(lane & 31) * 16,
                        xraw + i * 1024);
        }
        asm volatile("s_waitcnt vmcnt(0)" ::: "memory");
        __syncthreads();

        // ---- pack x: 16 rows/wave, lane-adjacent ds_read (no conflicts) ----
#pragma unroll
        for (int r = 0; r < 16; ++r) {
            const int row = wv * 16 + r;
            u64 v = *(const u64*)(xraw + (size_t)row * II + (size_t)lane * 8);
            u64 k = ballots8_bytes(v, lane);
            if (lane < 8) xp[row][lane] = k;
        }

        // ---- pipelined subtile loop ----
        for (int t = 0; t < NSUB; ++t) {
            // issue next subtile's DMA first: stream never stops
            if (t + 1 < NSUB) {
#pragma unroll
                for (int j = 0; j < 4; ++j) {
                    const int i = wv * 4 + j;
                    gload_lds16(wg + ((size_t)(t + 1) * SOT) * II
                                   + (size_t)i * 1024 + (size_t)lane * 16,
                                wraw[(t + 1) & 1] + i * 1024);
                }
            }
            // pack current subtile from wraw[t&1] (8 rows/wave)
#pragma unroll
            for (int j = 0; j < 8; ++j) {
                const int r = wv * 8 + j;
                u64 v = *(const u64*)(wraw[t & 1] + (size_t)r * II
                                                  + (size_t)lane * 8);
                u64 k = ballots8_bytes(v, lane);
                if (lane < 8) wp[r][lane] = k;
            }
            __syncthreads();     // wp (and xp at t=0) visible to all waves

            // Phase C: o = tid&31, b-range = (tid>>5)*8..+8
            const int ol = tid & 31;
            const int bg = tid >> 5;
            u64 wr[8];
#pragma unroll
            for (int k = 0; k < 8; ++k) wr[k] = wp[ol][k];
            int* outp = out + (size_t)d * OO + ob + t * SOT + ol;
#pragma unroll
            for (int bi = 0; bi < 8; ++bi) {
                const int b = bg * 8 + bi;
                int m = 0;
#pragma unroll
                for (int k = 0; k < 8; ++k) m += __popcll(xp[b][k] ^ wr[k]);
                const float act = (float)(II - m);   // exact integer in fp32
                outp[(size_t)b * (DD * OO)] = (act > bvv[t]) ? 1 : 0;
            }
            if (t + 1 < NSUB)
                asm volatile("s_waitcnt vmcnt(0)" ::: "memory"); // t+1 landed
            __syncthreads();     // wp free for overwrite; next buf ready
        }
    } else {
        // ---- fallback (int32/f32): ballot pack from global, per subtile ----
#pragma unroll
        for (int r = 0; r < 16; ++r) {
            const int b = wv * 16 + r;
            u64 my = pack_row_ballot(x, ((size_t)(b * DD + d)) * II, mode, lane);
            if (lane < 8) xp[b][lane] = my;
        }
        for (int t = 0; t < NSUB; ++t) {
#pragma unroll
            for (int j = 0; j < 8; ++j) {
                const int r = wv * 8 + j;
                const int o = ob + t * SOT + r;
                u64 my = pack_row_ballot(w, ((size_t)(d * OO + o)) * II, mode, lane);
                if (lane < 8) wp[r][lane] = my;
            }
            __syncthreads();
            const int ol = tid & 31;
            const int bg = tid >> 5;
            u64 wr[8];
#pragma unroll
            for (int k = 0; k < 8; ++k) wr[k] = wp[ol][k];
            int* outp = out + (size_t)d * OO + ob + t * SOT + ol;
#pragma unroll
            for (int bi = 0; bi < 8; ++bi) {
                const int b = bg * 8 + bi;
                int m = 0;
#pragma unroll
                for (int k = 0; k < 8; ++k) m += __popcll(xp[b][k] ^ wr[k]);
                const float act = (float)(II - m);
                outp[(size_t)b * (DD * OO)] = (act > bvv[t]) ? 1 : 0;
            }
            __syncthreads();
        }
    }
}

extern "C" void kernel_launch(void* const* d_in, const int* in_sizes, int n_in,
                              void* d_out, int out_size, void* d_ws, size_t ws_size,
                              hipStream_t stream) {
    const void*  x    = d_in[0];                 // (B, D, I) binary bytes
    const void*  w    = d_in[1];                 // (D, O, I) binary bytes
    const float* bias = (const float*)d_in[2];   // (D, O) f32
    int*         out  = (int*)d_out;             // (B, D, O) bool as int32

    binlin_stream<<<DD * (OO / BOT), 256, 0, stream>>>(x, w, bias, out);
}